// Round 2
// baseline (708.731 us; speedup 1.0000x reference)
//
#include <hip/hip_runtime.h>

#define LOG2E 1.44269504088896340736f

typedef _Float16 half2_t __attribute__((ext_vector_type(2)));

__device__ __forceinline__ float rlf(float v, int lane) {
    return __int_as_float(__builtin_amdgcn_readlane(__float_as_int(v), lane));
}
__device__ __forceinline__ unsigned rlu(unsigned v, int lane) {
    return (unsigned)__builtin_amdgcn_readlane((int)v, lane);
}
__device__ __forceinline__ unsigned pack2(float a, float b) {
    half2_t v; v.x = (_Float16)a; v.y = (_Float16)b;   // RNE (setup only)
    return __builtin_bit_cast(unsigned, v);
}
__device__ __forceinline__ half2_t ubc(unsigned u) {
    return __builtin_bit_cast(half2_t, u);
}

// Cross-half partner (lane^32) on the VALU pipe. xor-trick is convention-
// independent (round-9 verified PASS). Keep this form.
__device__ __forceinline__ float swap_half(float v) {
#if __has_builtin(__builtin_amdgcn_permlane32_swap)
    const unsigned u = __builtin_bit_cast(unsigned, v);
    auto r = __builtin_amdgcn_permlane32_swap(u, u, false, false);
    return __builtin_bit_cast(float, (unsigned)(r[0] ^ r[1] ^ u));
#else
    return __shfl_xor(v, 32, 64);     // DS fallback (round-5 proven)
#endif
}

// Neighbor (lane^1) via DPP quad_perm [1,0,3,2] — VALU, hazard-handled.
__device__ __forceinline__ float xor1_dpp(float v) {
    return __int_as_float(__builtin_amdgcn_mov_dpp(
        __float_as_int(v), 0xB1, 0xF, 0xF, true));
}

// Round-15: TWO independent sequences per wave as two interleavable
// INSTRUCTION streams (round-14 post-mortem: lane-split sequences share one
// dep chain and give zero overlap; per-step = issue + full path). Each seq
// uses the proven round-13 64-lane layout & hybrid broadcast; weights (the
// 32 big VGPRs) are shared. Seq B's issue fills seq A's dependency bubbles
// (measured: VALU dep ~12 cyc, trans ~20 cyc, path ~300 cyc/step, issue
// ~170 cyc/step). Grid 512: wall time = per-wave serial time, so idle
// SIMDs don't matter; per-step-pair target ~400 cyc vs 2x469.
__global__ __launch_bounds__(64, 1) void lstm_dual_kernel(
    const float* __restrict__ x,      // [B, T]
    const float* __restrict__ W_ih,   // [128]
    const float* __restrict__ W_hh,   // [128, 32]
    const float* __restrict__ b_ih,   // [128]
    const float* __restrict__ b_hh,   // [128]
    const float* __restrict__ W_out,  // [32]
    const float* __restrict__ b_out,  // [1]
    float* __restrict__ out,          // [B, T]
    int T)
{
    __shared__ float psumA[64 * 68];            // [step][lane] raw h, seq A
    __shared__ float psumB[64 * 68];            // seq B
    __shared__ __align__(16) unsigned hbcA[80]; // h-pair broadcast, seq A
    __shared__ __align__(16) unsigned hbcB[80]; // seq B

    const int b = blockIdx.x;
    const int l = threadIdx.x;        // 0..63
    const int r0 = l;                 // i (l<32) / f (l>=32): sigmoid rows
    const int r1 = l + 64;            // g (l<32) / o (l>=32)
    const bool lo = (l < 32);

    const float sc0 = -LOG2E;                           // sigmoid prescale
    const float sc1 = lo ? (-2.0f * LOG2E) : (-LOG2E);  // tanh / sigmoid

    // Pack prescaled W_hh rows into f16 pairs: 32 resident VGPRs, SHARED
    // by both sequences (the whole point of pairing them in one wave).
    unsigned w0u[16], w1u[16];
#pragma unroll
    for (int m = 0; m < 16; ++m) {
        w0u[m] = pack2(W_hh[r0 * 32 + 2 * m] * sc0,
                       W_hh[r0 * 32 + 2 * m + 1] * sc0);
        w1u[m] = pack2(W_hh[r1 * 32 + 2 * m] * sc1,
                       W_hh[r1 * 32 + 2 * m + 1] * sc1);
    }
#pragma unroll
    for (int m = 0; m < 16; ++m)
        asm volatile("" : "+v"(w0u[m]), "+v"(w1u[m]));  // pin; no remat

    // Epilogue W_out tiles.
    float4 wout4[8];
#pragma unroll
    for (int m = 0; m < 8; ++m)
        wout4[m] = *(const float4*)(W_out + 4 * m);

    const float wih0  = W_ih[r0] * sc0;
    const float wih1  = W_ih[r1] * sc1;
    const float bias0 = (b_ih[r0] + b_hh[r0]) * sc0;
    const float bias1 = (b_ih[r1] + b_hh[r1]) * sc1;
    // s1s: lanes<32 -> -2log2e * tanh(g); lanes>=32 -> sigmoid(o)
    const float A1s = lo ? (-4.0f * LOG2E) : 1.0f;
    const float B1s = lo ? ( 2.0f * LOG2E) : 0.0f;
    const float bout  = b_out[0];

    // Pairs 4..15 publishers (lanes 8,10,..,30) -> slots 4..15; rest park.
    const bool pub = lo && !(l & 1) && (l >= 8);
    const int waddr = pub ? (l >> 1) : (16 + l);

    float hA = 0.0f, csA = 0.0f;      // cs = -2*log2e*c (scaled cell state)
    float hB = 0.0f, csB = 0.0f;
    unsigned hpkA = 0u, hpkB = 0u;    // loop-carried packed pairs
    uint4 hqAB = {0,0,0,0}, hqAC = {0,0,0,0}, hqAD = {0,0,0,0};
    uint4 hqBB = {0,0,0,0}, hqBC = {0,0,0,0}, hqBD = {0,0,0,0};

    const float* xpA = x + (size_t)(2 * b)     * T;
    const float* xpB = x + (size_t)(2 * b + 1) * T;
    float*       opA = out + (size_t)(2 * b)     * T;
    float*       opB = out + (size_t)(2 * b + 1) * T;
    float xvA = xpA[l];
    float xvB = xpB[l];

    const uint4* hb4A = (const uint4*)hbcA;
    const uint4* hb4B = (const uint4*)hbcB;

    for (int t0 = 0; t0 < T; t0 += 64) {
        const int tn = (t0 + 64 < T) ? (t0 + 64) : t0;
        float nA = xpA[tn + l];       // prefetch next chunk
        float nB = xpB[tn + l];

#pragma unroll 8
        for (int tu = 0; tu < 64; ++tu) {
            const float xtA = rlf(xvA, tu);
            const float xtB = rlf(xvB, tu);

            // Pairs 0..3 via readlane (register path; feeds chain heads,
            // covering the LDS broadcast latency of hq*).
            const unsigned hA0 = rlu(hpkA, 0), hA1 = rlu(hpkA, 2);
            const unsigned hA2 = rlu(hpkA, 4), hA3 = rlu(hpkA, 6);
            const unsigned hB0 = rlu(hpkB, 0), hB1 = rlu(hpkB, 2);
            const unsigned hB2 = rlu(hpkB, 4), hB3 = rlu(hpkB, 6);

            float a0A = fmaf(wih0, xtA, bias0);
            float a1A = fmaf(wih1, xtA, bias1);
            float b0A = 0.0f, b1A = 0.0f;
            float a0B = fmaf(wih0, xtB, bias0);
            float a1B = fmaf(wih1, xtB, bias1);
            float b0B = 0.0f, b1B = 0.0f;

#define FD(acc, w, h) acc = __builtin_amdgcn_fdot2(ubc(w), ubc(h), acc, false)
            // Readlane-fed dots (A then B; independent chains interleave).
            FD(a0A, w0u[0], hA0);  FD(b0A, w0u[1], hA1);
            FD(a1A, w1u[0], hA0);  FD(b1A, w1u[1], hA1);
            FD(a0B, w0u[0], hB0);  FD(b0B, w0u[1], hB1);
            FD(a1B, w1u[0], hB0);  FD(b1B, w1u[1], hB1);
            FD(a0A, w0u[2], hA2);  FD(b0A, w0u[3], hA3);
            FD(a1A, w1u[2], hA2);  FD(b1A, w1u[3], hA3);
            FD(a0B, w0u[2], hB2);  FD(b0B, w0u[3], hB3);
            FD(a1B, w1u[2], hB2);  FD(b1B, w1u[3], hB3);
            // LDS-broadcast-fed dots, seq A.
            FD(a0A, w0u[4],  hqAB.x);  FD(b0A, w0u[5],  hqAB.y);
            FD(a1A, w1u[4],  hqAB.x);  FD(b1A, w1u[5],  hqAB.y);
            FD(a0A, w0u[6],  hqAB.z);  FD(b0A, w0u[7],  hqAB.w);
            FD(a1A, w1u[6],  hqAB.z);  FD(b1A, w1u[7],  hqAB.w);
            FD(a0A, w0u[8],  hqAC.x);  FD(b0A, w0u[9],  hqAC.y);
            FD(a1A, w1u[8],  hqAC.x);  FD(b1A, w1u[9],  hqAC.y);
            FD(a0A, w0u[10], hqAC.z);  FD(b0A, w0u[11], hqAC.w);
            FD(a1A, w1u[10], hqAC.z);  FD(b1A, w1u[11], hqAC.w);
            FD(a0A, w0u[12], hqAD.x);  FD(b0A, w0u[13], hqAD.y);
            FD(a1A, w1u[12], hqAD.x);  FD(b1A, w1u[13], hqAD.y);
            FD(a0A, w0u[14], hqAD.z);  FD(b0A, w0u[15], hqAD.w);
            FD(a1A, w1u[14], hqAD.z);  FD(b1A, w1u[15], hqAD.w);
            // LDS-broadcast-fed dots, seq B.
            FD(a0B, w0u[4],  hqBB.x);  FD(b0B, w0u[5],  hqBB.y);
            FD(a1B, w1u[4],  hqBB.x);  FD(b1B, w1u[5],  hqBB.y);
            FD(a0B, w0u[6],  hqBB.z);  FD(b0B, w0u[7],  hqBB.w);
            FD(a1B, w1u[6],  hqBB.z);  FD(b1B, w1u[7],  hqBB.w);
            FD(a0B, w0u[8],  hqBC.x);  FD(b0B, w0u[9],  hqBC.y);
            FD(a1B, w1u[8],  hqBC.x);  FD(b1B, w1u[9],  hqBC.y);
            FD(a0B, w0u[10], hqBC.z);  FD(b0B, w0u[11], hqBC.w);
            FD(a1B, w1u[10], hqBC.z);  FD(b1B, w1u[11], hqBC.w);
            FD(a0B, w0u[12], hqBD.x);  FD(b0B, w0u[13], hqBD.y);
            FD(a1B, w1u[12], hqBD.x);  FD(b1B, w1u[13], hqBD.y);
            FD(a0B, w0u[14], hqBD.z);  FD(b0B, w0u[15], hqBD.w);
            FD(a1B, w1u[14], hqBD.z);  FD(b1B, w1u[15], hqBD.w);
#undef FD

            const float GA0 = a0A + b0A;
            const float GA1 = a1A + b1A;
            const float GB0 = a0B + b0B;
            const float GB1 = a1B + b1B;

            // s0 = sigmoid(i|f); s1s = -2log2e*tanh(g) (lo) | sigmoid(o)
            const float s0A  = __builtin_amdgcn_rcpf(1.0f + __builtin_amdgcn_exp2f(GA0));
            const float s0B  = __builtin_amdgcn_rcpf(1.0f + __builtin_amdgcn_exp2f(GB0));
            const float s1sA = fmaf(A1s, __builtin_amdgcn_rcpf(
                                   1.0f + __builtin_amdgcn_exp2f(GA1)), B1s);
            const float s1sB = fmaf(A1s, __builtin_amdgcn_rcpf(
                                   1.0f + __builtin_amdgcn_exp2f(GB1)), B1s);
            const float igA = s0A * s1sA;       // i*(-2log2e*g), pre-swap
            const float igB = s0B * s1sB;

            // VALU cross-half exchange: lanes<32 get (f, sigmoid(o)).
            const float o0A = swap_half(s0A);
            const float o1A = swap_half(s1sA);
            const float o0B = swap_half(s0B);
            const float o1B = swap_half(s1sB);
            const float to1A = o1A + o1A;       // off critical path
            const float to1B = o1B + o1B;

            // cs = f*cs + i*(-2log2e*g); h = o1*tanh(c) = 2*o1*rcp - o1
            csA = fmaf(o0A, csA, igA);
            csB = fmaf(o0B, csB, igB);
            const float rcA = __builtin_amdgcn_rcpf(
                1.0f + __builtin_amdgcn_exp2f(csA));
            const float rcB = __builtin_amdgcn_rcpf(
                1.0f + __builtin_amdgcn_exp2f(csB));
            hA = fmaf(to1A, rcA, -o1A);
            hB = fmaf(to1B, rcB, -o1B);

            // Pack pairs; publish 4..15 to LDS; pre-read next step's
            // broadcast (same-wave DS ops in-order -> reads see writes).
            const float hnA = xor1_dpp(hA);
            const float hnB = xor1_dpp(hB);
            hpkA = __builtin_bit_cast(unsigned,
                       __builtin_amdgcn_cvt_pkrtz(hA, hnA));
            hpkB = __builtin_bit_cast(unsigned,
                       __builtin_amdgcn_cvt_pkrtz(hB, hnB));
            hbcA[waddr] = hpkA;
            hbcB[waddr] = hpkB;
            psumA[tu * 68 + l] = hA;            // raw h; W_out in epilogue
            psumB[tu * 68 + l] = hB;
            hqAB = hb4A[1];                     // uniform addr = broadcast;
            hqAC = hb4A[2];                     // latency covered by next
            hqAD = hb4A[3];                     // step's readlane-fed dots
            hqBB = hb4B[1];
            hqBC = hb4B[2];
            hqBD = hb4B[3];
        }

        __syncthreads();  // single wave: cheap; drains psum + pending reads
        // Lane j: out[t0+j] = sum_{k<32} psum[j][k] * W_out[k], per seq.
#pragma unroll
        for (int s = 0; s < 2; ++s) {
            const float* ps = (s == 0) ? psumA : psumB;
            const float4* row = (const float4*)(ps + l * 68);
            float4 s4;
            {
                float4 v4 = row[0];
                s4.x = v4.x * wout4[0].x; s4.y = v4.y * wout4[0].y;
                s4.z = v4.z * wout4[0].z; s4.w = v4.w * wout4[0].w;
            }
#pragma unroll
            for (int m = 1; m < 8; ++m) {
                float4 v4 = row[m];
                s4.x = fmaf(v4.x, wout4[m].x, s4.x);
                s4.y = fmaf(v4.y, wout4[m].y, s4.y);
                s4.z = fmaf(v4.z, wout4[m].z, s4.z);
                s4.w = fmaf(v4.w, wout4[m].w, s4.w);
            }
            const float r = (s4.x + s4.y) + (s4.z + s4.w) + bout;
            if (s == 0) opA[t0 + l] = r; else opB[t0 + l] = r;
        }
        __syncthreads();  // next chunk overwrites psum (hbc untouched)
        xvA = nA;
        xvB = nB;
    }
}

extern "C" void kernel_launch(void* const* d_in, const int* in_sizes, int n_in,
                              void* d_out, int out_size, void* d_ws, size_t ws_size,
                              hipStream_t stream) {
    const float* x     = (const float*)d_in[0];   // [1024, 2048, 1]
    const float* W_ih  = (const float*)d_in[1];   // [128, 1]
    const float* W_hh  = (const float*)d_in[2];   // [128, 32]
    const float* b_ih  = (const float*)d_in[3];   // [128]
    const float* b_hh  = (const float*)d_in[4];   // [128]
    const float* W_out = (const float*)d_in[5];   // [1, 32]
    const float* b_out = (const float*)d_in[6];   // [1]
    float* out = (float*)d_out;                   // [1024, 2048, 1]

    const int B = 1024;
    const int T = 2048;
    lstm_dual_kernel<<<B / 2, 64, 0, stream>>>(x, W_ih, W_hh, b_ih, b_hh,
                                               W_out, b_out, out, T);
}

// Round 3
// 450.755 us; speedup vs baseline: 1.5723x; 1.5723x over previous
//
#include <hip/hip_runtime.h>

#define LOG2E 1.44269504088896340736f

typedef _Float16 half2_t __attribute__((ext_vector_type(2)));

__device__ __forceinline__ float rlf(float v, int lane) {
    return __int_as_float(__builtin_amdgcn_readlane(__float_as_int(v), lane));
}
__device__ __forceinline__ unsigned rlu(unsigned v, int lane) {
    return (unsigned)__builtin_amdgcn_readlane((int)v, lane);
}
__device__ __forceinline__ unsigned pack2(float a, float b) {
    half2_t v; v.x = (_Float16)a; v.y = (_Float16)b;   // RNE (setup only)
    return __builtin_bit_cast(unsigned, v);
}
__device__ __forceinline__ half2_t ubc(unsigned u) {
    return __builtin_bit_cast(half2_t, u);
}

// Cross-half partner (lane^32) on the VALU pipe (round-9 verified form).
__device__ __forceinline__ float swap_half(float v) {
#if __has_builtin(__builtin_amdgcn_permlane32_swap)
    const unsigned u = __builtin_bit_cast(unsigned, v);
    auto r = __builtin_amdgcn_permlane32_swap(u, u, false, false);
    return __builtin_bit_cast(float, (unsigned)(r[0] ^ r[1] ^ u));
#else
    return __shfl_xor(v, 32, 64);     // DS fallback (round-5 proven)
#endif
}

// Neighbor (lane^1) via DPP quad_perm [1,0,3,2] — VALU, hazard-handled.
__device__ __forceinline__ float xor1_dpp(float v) {
    return __int_as_float(__builtin_amdgcn_mov_dpp(
        __float_as_int(v), 0xB1, 0xF, 0xF, true));
}

// Round-16: R13 base (429 us verified; full-chip 1 wave/SIMD — rounds 14/15
// proved dual-seq waves lose on wall clock) with three carried-path cuts:
//  (a) dot chains split 8-deep -> 2x4-deep (8 accumulators, merge tree):
//      ~50 cyc off the hpk->G path for +6 adds of issue.
//  (b) h published to LDS as a 2-byte f16 store right after h is computed
//      (lanes 8..31 each store their own half of pairs 4..15 — identical
//      memory image to the old packed-u32 publish); dpp+pkrtz (readlane
//      path only) moved after the broadcast reads. Publish->read slack
//      grows ~25 cyc against the ~200-cyc DS round trip.
//  (c) hqC/hqD-fed dots (operands in regs from last step) issue first,
//      covering the 8 readlane->SGPR hazards; readlane/hqB dots follow.
__global__ __launch_bounds__(64, 1) void lstm_pl_kernel(
    const float* __restrict__ x,      // [B, T]
    const float* __restrict__ W_ih,   // [128]
    const float* __restrict__ W_hh,   // [128, 32]
    const float* __restrict__ b_ih,   // [128]
    const float* __restrict__ b_hh,   // [128]
    const float* __restrict__ W_out,  // [32]
    const float* __restrict__ b_out,  // [1]
    float* __restrict__ out,          // [B, T]
    int T)
{
    __shared__ float psum[64 * 68];            // [step][lane] raw h
    __shared__ __align__(16) unsigned hbc[80]; // h broadcast: pairs 4..15 at
                                               // bytes 16..63; bytes >=160 park
    const int b = blockIdx.x;
    const int l = threadIdx.x;        // 0..63
    const int r0 = l;                 // i (l<32) / f (l>=32): sigmoid rows
    const int r1 = l + 64;            // g (l<32) / o (l>=32)
    const bool lo = (l < 32);

    const float sc0 = -LOG2E;                           // sigmoid prescale
    const float sc1 = lo ? (-2.0f * LOG2E) : (-LOG2E);  // tanh / sigmoid

    // Pack prescaled W_hh rows into f16 pairs: 32 resident VGPRs.
    unsigned w0u[16], w1u[16];
#pragma unroll
    for (int m = 0; m < 16; ++m) {
        w0u[m] = pack2(W_hh[r0 * 32 + 2 * m] * sc0,
                       W_hh[r0 * 32 + 2 * m + 1] * sc0);
        w1u[m] = pack2(W_hh[r1 * 32 + 2 * m] * sc1,
                       W_hh[r1 * 32 + 2 * m + 1] * sc1);
    }
#pragma unroll
    for (int m = 0; m < 16; ++m)
        asm volatile("" : "+v"(w0u[m]), "+v"(w1u[m]));  // pin; no remat

    // Epilogue W_out tiles.
    float4 wout4[8];
#pragma unroll
    for (int m = 0; m < 8; ++m)
        wout4[m] = *(const float4*)(W_out + 4 * m);

    const float wih0  = W_ih[r0] * sc0;
    const float wih1  = W_ih[r1] * sc1;
    const float bias0 = (b_ih[r0] + b_hh[r0]) * sc0;
    const float bias1 = (b_ih[r1] + b_hh[r1]) * sc1;
    // s1s: lanes<32 -> -2log2e * tanh(g); lanes>=32 -> sigmoid(o)
    const float A1s = lo ? (-4.0f * LOG2E) : 1.0f;
    const float B1s = lo ? ( 2.0f * LOG2E) : 0.0f;
    const float bout  = b_out[0];

    // f16 publish: lanes 8..31 write h of unit l at byte 2l (pairs 4..15);
    // all other lanes park at bytes 160+2l (never read; buffer is 320 B).
    _Float16* hb16 = (_Float16*)hbc;
    const bool pub16 = lo && (l >= 8);
    const int waddr16 = pub16 ? l : (80 + l);   // element (2-byte) index

    float h = 0.0f, cs = 0.0f;        // cs = -2*log2e*c  (scaled cell state)
    unsigned hpk = 0u;                // loop-carried packed pair (readlane src)
    // Loop-carried LDS-broadcast pairs 4..15 (step 0: h == 0).
    uint4 hqB = {0,0,0,0}, hqC = {0,0,0,0}, hqD = {0,0,0,0};

    const float* xp = x + (size_t)b * T;
    float*       op = out + (size_t)b * T;
    float xv = xp[l];

    const uint4* hb4 = (const uint4*)hbc;

    for (int t0 = 0; t0 < T; t0 += 64) {
        const int tn = (t0 + 64 < T) ? (t0 + 64) : t0;
        float xv_next = xp[tn + l];   // prefetch next chunk

#pragma unroll 16
        for (int tu = 0; tu < 64; ++tu) {
            const float xt = rlf(xv, tu);

            // Pairs 0..3 via readlane (register path; feeds a/b chains).
            const unsigned hp0 = rlu(hpk, 0);
            const unsigned hp1 = rlu(hpk, 2);
            const unsigned hp2 = rlu(hpk, 4);
            const unsigned hp3 = rlu(hpk, 6);

            float a0 = fmaf(wih0, xt, bias0);
            float a1 = fmaf(wih1, xt, bias1);
            float b0 = 0.0f, b1 = 0.0f;
            float c0 = 0.0f, c1 = 0.0f, d0 = 0.0f, d1 = 0.0f;

#define FD(acc, w, hh) acc = __builtin_amdgcn_fdot2(ubc(w), ubc(hh), acc, false)
            // Register-resident dots first (hqC/hqD read last step) —
            // these cover the readlane->SGPR hazard window.
            FD(c0, w0u[8],  hqC.x);  FD(d0, w0u[9],  hqC.y);
            FD(c1, w1u[8],  hqC.x);  FD(d1, w1u[9],  hqC.y);
            FD(c0, w0u[10], hqC.z);  FD(d0, w0u[11], hqC.w);
            FD(c1, w1u[10], hqC.z);  FD(d1, w1u[11], hqC.w);
            FD(c0, w0u[12], hqD.x);  FD(d0, w0u[13], hqD.y);
            FD(c1, w1u[12], hqD.x);  FD(d1, w1u[13], hqD.y);
            FD(c0, w0u[14], hqD.z);  FD(d0, w0u[15], hqD.w);
            FD(c1, w1u[14], hqD.z);  FD(d1, w1u[15], hqD.w);
            // Readlane-fed dots (4-deep chains a/b start here).
            FD(a0, w0u[0],  hp0);    FD(b0, w0u[1],  hp1);
            FD(a1, w1u[0],  hp0);    FD(b1, w1u[1],  hp1);
            FD(a0, w0u[2],  hp2);    FD(b0, w0u[3],  hp3);
            FD(a1, w1u[2],  hp2);    FD(b1, w1u[3],  hp3);
            // hqB-fed dots complete the a/b chains.
            FD(a0, w0u[4],  hqB.x);  FD(b0, w0u[5],  hqB.y);
            FD(a1, w1u[4],  hqB.x);  FD(b1, w1u[5],  hqB.y);
            FD(a0, w0u[6],  hqB.z);  FD(b0, w0u[7],  hqB.w);
            FD(a1, w1u[6],  hqB.z);  FD(b1, w1u[7],  hqB.w);
#undef FD
            const float G0 = (a0 + b0) + (c0 + d0);
            const float G1 = (a1 + b1) + (c1 + d1);

            // s0 = sigmoid(i|f); s1s = -2log2e*tanh(g) (lo) | sigmoid(o)
            const float s0  = __builtin_amdgcn_rcpf(1.0f + __builtin_amdgcn_exp2f(G0));
            const float s1s = fmaf(A1s, __builtin_amdgcn_rcpf(
                                  1.0f + __builtin_amdgcn_exp2f(G1)), B1s);
            const float ig = s0 * s1s;           // i*(-2log2e*g), pre-swap

            // VALU cross-half exchange: lanes<32 get (f, sigmoid(o)).
            const float o0 = swap_half(s0);
            const float o1 = swap_half(s1s);
            const float to1 = o1 + o1;           // off critical path

            // cs = f*cs + i*(-2log2e*g); h = o1*tanh(c) = 2*o1*rcp - o1
            cs = fmaf(o0, cs, ig);
            const float rc = __builtin_amdgcn_rcpf(
                1.0f + __builtin_amdgcn_exp2f(cs));
            h = fmaf(to1, rc, -o1);

            // EARLY publish: single f16 store straight off h (no dpp/pack
            // on this path), then the broadcast reads (same-wave DS ops are
            // in-order, so the reads see this write).
            hb16[waddr16] = (_Float16)h;
            hqB = hb4[1];
            hqC = hb4[2];
            hqD = hb4[3];
            psum[tu * 68 + l] = h;               // raw h; W_out in epilogue

            // Pack pair for next step's readlanes (off the publish path).
            const float hn = xor1_dpp(h);
            hpk = __builtin_bit_cast(unsigned,
                      __builtin_amdgcn_cvt_pkrtz(h, hn));
        }

        __syncthreads();  // single wave: cheap; drains psum + pending reads
        // Lane j: out[t0+j] = sum_{k<32} psum[j][k] * W_out[k].
        const float4* row = (const float4*)(psum + l * 68);
        float4 s4;
        {
            float4 v4 = row[0];
            s4.x = v4.x * wout4[0].x; s4.y = v4.y * wout4[0].y;
            s4.z = v4.z * wout4[0].z; s4.w = v4.w * wout4[0].w;
        }
#pragma unroll
        for (int m = 1; m < 8; ++m) {
            float4 v4 = row[m];
            s4.x = fmaf(v4.x, wout4[m].x, s4.x);
            s4.y = fmaf(v4.y, wout4[m].y, s4.y);
            s4.z = fmaf(v4.z, wout4[m].z, s4.z);
            s4.w = fmaf(v4.w, wout4[m].w, s4.w);
        }
        op[t0 + l] = (s4.x + s4.y) + (s4.z + s4.w) + bout;
        __syncthreads();  // next chunk overwrites psum (hbc untouched)
        xv = xv_next;
    }
}

extern "C" void kernel_launch(void* const* d_in, const int* in_sizes, int n_in,
                              void* d_out, int out_size, void* d_ws, size_t ws_size,
                              hipStream_t stream) {
    const float* x     = (const float*)d_in[0];   // [1024, 2048, 1]
    const float* W_ih  = (const float*)d_in[1];   // [128, 1]
    const float* W_hh  = (const float*)d_in[2];   // [128, 32]
    const float* b_ih  = (const float*)d_in[3];   // [128]
    const float* b_hh  = (const float*)d_in[4];   // [128]
    const float* W_out = (const float*)d_in[5];   // [1, 32]
    const float* b_out = (const float*)d_in[6];   // [1]
    float* out = (float*)d_out;                   // [1024, 2048, 1]

    const int B = 1024;
    const int T = 2048;
    lstm_pl_kernel<<<B, 64, 0, stream>>>(x, W_ih, W_hh, b_ih, b_hh,
                                         W_out, b_out, out, T);
}

// Round 4
// 419.847 us; speedup vs baseline: 1.6881x; 1.0736x over previous
//
#include <hip/hip_runtime.h>

#define LOG2E 1.44269504088896340736f

typedef _Float16 half2_t __attribute__((ext_vector_type(2)));

__device__ __forceinline__ float rlf(float v, int lane) {
    return __int_as_float(__builtin_amdgcn_readlane(__float_as_int(v), lane));
}
__device__ __forceinline__ unsigned rlu(unsigned v, int lane) {
    return (unsigned)__builtin_amdgcn_readlane((int)v, lane);
}
__device__ __forceinline__ unsigned pack2(float a, float b) {
    half2_t v; v.x = (_Float16)a; v.y = (_Float16)b;   // RNE (setup only)
    return __builtin_bit_cast(unsigned, v);
}
__device__ __forceinline__ half2_t ubc(unsigned u) {
    return __builtin_bit_cast(half2_t, u);
}

// Cross-half partner (lane^32) on the VALU pipe (round-9 verified form).
__device__ __forceinline__ float swap_half(float v) {
#if __has_builtin(__builtin_amdgcn_permlane32_swap)
    const unsigned u = __builtin_bit_cast(unsigned, v);
    auto r = __builtin_amdgcn_permlane32_swap(u, u, false, false);
    return __builtin_bit_cast(float, (unsigned)(r[0] ^ r[1] ^ u));
#else
    return __shfl_xor(v, 32, 64);     // DS fallback (round-5 proven)
#endif
}

// Neighbor (lane^1) via DPP quad_perm [1,0,3,2] — VALU, hazard-handled.
__device__ __forceinline__ float xor1_dpp(float v) {
    return __int_as_float(__builtin_amdgcn_mov_dpp(
        __float_as_int(v), 0xB1, 0xF, 0xF, true));
}

// Round-17: readlane-ONLY h broadcast — ZERO DS ops on the recurrence path.
// Evidence: R12 (all-LDS), R13 (hybrid), R16 (hybrid reordered) all pin at
// ~470-500 cyc/step with real VALU issue only ~36% (VALUBusy 72-75 under the
// 4cyc/inst gfx94x formula). Dep-chain micro-cuts (R16) moved nothing, so
// the ~300-cyc stall is attributed to the LDS write->read round trip
// (~200 cyc) that every prior variant kept on the loop. Here pair p
// (h[2p],h[2p+1]) is read from lane 2p of the loop-carried packed register
// hpk via v_readlane (16/step, ~6 cyc each incl. hazards per R13's measured
// +24cyc/4). Readlanes are batched 4-at-a-time between dot groups so the
// SGPR-write->VALU-read hazard window (~4 insts) is always covered by dots.
// Only remaining DS op in the loop: the psum store (write-only, no wait).
__global__ __launch_bounds__(64, 1) void lstm_pl_kernel(
    const float* __restrict__ x,      // [B, T]
    const float* __restrict__ W_ih,   // [128]
    const float* __restrict__ W_hh,   // [128, 32]
    const float* __restrict__ b_ih,   // [128]
    const float* __restrict__ b_hh,   // [128]
    const float* __restrict__ W_out,  // [32]
    const float* __restrict__ b_out,  // [1]
    float* __restrict__ out,          // [B, T]
    int T)
{
    __shared__ float psum[64 * 68];   // [step][lane] raw h

    const int b = blockIdx.x;
    const int l = threadIdx.x;        // 0..63
    const int r0 = l;                 // i (l<32) / f (l>=32): sigmoid rows
    const int r1 = l + 64;            // g (l<32) / o (l>=32)
    const bool lo = (l < 32);

    const float sc0 = -LOG2E;                           // sigmoid prescale
    const float sc1 = lo ? (-2.0f * LOG2E) : (-LOG2E);  // tanh / sigmoid

    // Pack prescaled W_hh rows into f16 pairs: 32 resident VGPRs.
    // w0u[m]/w1u[m] multiply h-pair m = (h[2m], h[2m+1]).
    unsigned w0u[16], w1u[16];
#pragma unroll
    for (int m = 0; m < 16; ++m) {
        w0u[m] = pack2(W_hh[r0 * 32 + 2 * m] * sc0,
                       W_hh[r0 * 32 + 2 * m + 1] * sc0);
        w1u[m] = pack2(W_hh[r1 * 32 + 2 * m] * sc1,
                       W_hh[r1 * 32 + 2 * m + 1] * sc1);
    }
#pragma unroll
    for (int m = 0; m < 16; ++m)
        asm volatile("" : "+v"(w0u[m]), "+v"(w1u[m]));  // pin; no remat

    // Epilogue W_out tiles.
    float4 wout4[8];
#pragma unroll
    for (int m = 0; m < 8; ++m)
        wout4[m] = *(const float4*)(W_out + 4 * m);

    const float wih0  = W_ih[r0] * sc0;
    const float wih1  = W_ih[r1] * sc1;
    const float bias0 = (b_ih[r0] + b_hh[r0]) * sc0;
    const float bias1 = (b_ih[r1] + b_hh[r1]) * sc1;
    // s1s: lanes<32 -> -2log2e * tanh(g); lanes>=32 -> sigmoid(o)
    const float A1s = lo ? (-4.0f * LOG2E) : 1.0f;
    const float B1s = lo ? ( 2.0f * LOG2E) : 0.0f;
    const float bout  = b_out[0];

    float h = 0.0f, cs = 0.0f;        // cs = -2*log2e*c  (scaled cell state)
    unsigned hpk = 0u;                // loop-carried packed pair (readlane src)

    const float* xp = x + (size_t)b * T;
    float*       op = out + (size_t)b * T;
    float xv = xp[l];

    for (int t0 = 0; t0 < T; t0 += 64) {
        const int tn = (t0 + 64 < T) ? (t0 + 64) : t0;
        float xv_next = xp[tn + l];   // prefetch next chunk

#pragma unroll 16
        for (int tu = 0; tu < 64; ++tu) {
            const float xt = rlf(xv, tu);

            // Pair p lives in lane 2p of hpk. Batch 4 readlanes, then 16
            // dots, repeat — spacing covers all readlane hazards.
            const unsigned q0 = rlu(hpk, 0);
            const unsigned q1 = rlu(hpk, 2);
            const unsigned q2 = rlu(hpk, 4);
            const unsigned q3 = rlu(hpk, 6);

            float a0 = fmaf(wih0, xt, bias0);
            float a1 = fmaf(wih1, xt, bias1);
            float b0 = 0.0f, b1 = 0.0f;

#define FD(acc, w, hh) acc = __builtin_amdgcn_fdot2(ubc(w), ubc(hh), acc, false)
            FD(a0, w0u[0],  q0);  FD(b0, w0u[1],  q1);
            FD(a1, w1u[0],  q0);  FD(b1, w1u[1],  q1);
            const unsigned q4 = rlu(hpk, 8);
            const unsigned q5 = rlu(hpk, 10);
            const unsigned q6 = rlu(hpk, 12);
            const unsigned q7 = rlu(hpk, 14);
            FD(a0, w0u[2],  q2);  FD(b0, w0u[3],  q3);
            FD(a1, w1u[2],  q2);  FD(b1, w1u[3],  q3);
            const unsigned q8 = rlu(hpk, 16);
            const unsigned q9 = rlu(hpk, 18);
            const unsigned qA = rlu(hpk, 20);
            const unsigned qB = rlu(hpk, 22);
            FD(a0, w0u[4],  q4);  FD(b0, w0u[5],  q5);
            FD(a1, w1u[4],  q4);  FD(b1, w1u[5],  q5);
            const unsigned qC = rlu(hpk, 24);
            const unsigned qD = rlu(hpk, 26);
            const unsigned qE = rlu(hpk, 28);
            const unsigned qF = rlu(hpk, 30);
            FD(a0, w0u[6],  q6);  FD(b0, w0u[7],  q7);
            FD(a1, w1u[6],  q6);  FD(b1, w1u[7],  q7);
            FD(a0, w0u[8],  q8);  FD(b0, w0u[9],  q9);
            FD(a1, w1u[8],  q8);  FD(b1, w1u[9],  q9);
            FD(a0, w0u[10], qA);  FD(b0, w0u[11], qB);
            FD(a1, w1u[10], qA);  FD(b1, w1u[11], qB);
            FD(a0, w0u[12], qC);  FD(b0, w0u[13], qD);
            FD(a1, w1u[12], qC);  FD(b1, w1u[13], qD);
            FD(a0, w0u[14], qE);  FD(b0, w0u[15], qF);
            FD(a1, w1u[14], qE);  FD(b1, w1u[15], qF);
#undef FD
            const float G0 = a0 + b0;
            const float G1 = a1 + b1;

            // s0 = sigmoid(i|f); s1s = -2log2e*tanh(g) (lo) | sigmoid(o)
            const float s0  = __builtin_amdgcn_rcpf(1.0f + __builtin_amdgcn_exp2f(G0));
            const float s1s = fmaf(A1s, __builtin_amdgcn_rcpf(
                                  1.0f + __builtin_amdgcn_exp2f(G1)), B1s);
            const float ig = s0 * s1s;           // i*(-2log2e*g), pre-swap

            // VALU cross-half exchange: lanes<32 get (f, sigmoid(o)).
            const float o0 = swap_half(s0);
            const float o1 = swap_half(s1s);
            const float to1 = o1 + o1;           // off critical path

            // cs = f*cs + i*(-2log2e*g); h = o1*tanh(c) = 2*o1*rcp - o1
            cs = fmaf(o0, cs, ig);
            const float rc = __builtin_amdgcn_rcpf(
                1.0f + __builtin_amdgcn_exp2f(cs));
            h = fmaf(to1, rc, -o1);

            // Pack pair for next step's readlanes; store raw h for epilogue.
            const float hn = xor1_dpp(h);
            hpk = __builtin_bit_cast(unsigned,
                      __builtin_amdgcn_cvt_pkrtz(h, hn));
            psum[tu * 68 + l] = h;               // write-only; no wait in loop
        }

        __syncthreads();  // single wave: cheap; drains psum
        // Lane j: out[t0+j] = sum_{k<32} psum[j][k] * W_out[k].
        const float4* row = (const float4*)(psum + l * 68);
        float4 s4;
        {
            float4 v4 = row[0];
            s4.x = v4.x * wout4[0].x; s4.y = v4.y * wout4[0].y;
            s4.z = v4.z * wout4[0].z; s4.w = v4.w * wout4[0].w;
        }
#pragma unroll
        for (int m = 1; m < 8; ++m) {
            float4 v4 = row[m];
            s4.x = fmaf(v4.x, wout4[m].x, s4.x);
            s4.y = fmaf(v4.y, wout4[m].y, s4.y);
            s4.z = fmaf(v4.z, wout4[m].z, s4.z);
            s4.w = fmaf(v4.w, wout4[m].w, s4.w);
        }
        op[t0 + l] = (s4.x + s4.y) + (s4.z + s4.w) + bout;
        __syncthreads();  // next chunk overwrites psum
        xv = xv_next;
    }
}

extern "C" void kernel_launch(void* const* d_in, const int* in_sizes, int n_in,
                              void* d_out, int out_size, void* d_ws, size_t ws_size,
                              hipStream_t stream) {
    const float* x     = (const float*)d_in[0];   // [1024, 2048, 1]
    const float* W_ih  = (const float*)d_in[1];   // [128, 1]
    const float* W_hh  = (const float*)d_in[2];   // [128, 32]
    const float* b_ih  = (const float*)d_in[3];   // [128]
    const float* b_hh  = (const float*)d_in[4];   // [128]
    const float* W_out = (const float*)d_in[5];   // [1, 32]
    const float* b_out = (const float*)d_in[6];   // [1]
    float* out = (float*)d_out;                   // [1024, 2048, 1]

    const int B = 1024;
    const int T = 2048;
    lstm_pl_kernel<<<B, 64, 0, stream>>>(x, W_ih, W_hh, b_ih, b_hh,
                                         W_out, b_out, out, T);
}